// Round 17
// baseline (103.313 us; speedup 1.0000x reference)
//
#include <hip/hip_runtime.h>
#include <stdint.h>

#define NUM_H 16
#define HD    64
#define CDIM  1024
#define NSEQ  2048
#define NBATCH 2
#define LOG2E 1.4426950408889634f

typedef __attribute__((ext_vector_type(8))) short short8;
typedef __attribute__((ext_vector_type(4))) float f32x4;
typedef __attribute__((ext_vector_type(16))) float f32x16;
typedef __attribute__((ext_vector_type(4))) unsigned short ushort4v;
typedef __attribute__((ext_vector_type(4))) float float4v;
typedef __attribute__((ext_vector_type(2))) unsigned int u32x2;

__device__ __forceinline__ unsigned short f2bf(float f) {
    unsigned int u = __builtin_bit_cast(unsigned int, f);
    unsigned int r = u + 0x7fffu + ((u >> 16) & 1u);
    return (unsigned short)(r >> 16);
}

__device__ __forceinline__ unsigned int cvtpk(float a, float b) {
    unsigned int r;
    asm("v_cvt_pk_bf16_f32 %0, %1, %2" : "=v"(r) : "v"(a), "v"(b));
    return r;
}

__device__ __forceinline__ void plswap(unsigned int &a, unsigned int &b) {
    asm("v_permlane32_swap_b32 %0, %1" : "+v"(a), "+v"(b));
}

// global -> LDS async copy, 16B per lane. LDS dest is wave-uniform base + lane*16.
__device__ __forceinline__ void gload_lds16(const void* g, const void* l) {
    __builtin_amdgcn_global_load_lds(
        (const __attribute__((address_space(1))) unsigned int*)(unsigned long long)(uintptr_t)g,
        (__attribute__((address_space(3))) unsigned int*)(unsigned int)(uintptr_t)l,
        16, 0, 0);
}

// fused fp32->bf16 convert for x, qkv_w, proj_w (one launch)
__global__ void cvt_all_kernel(const float* __restrict__ x,
                               const float* __restrict__ w1,
                               const float* __restrict__ wp,
                               unsigned short* __restrict__ xo,
                               unsigned short* __restrict__ w1o,
                               unsigned short* __restrict__ wpo) {
    int i = blockIdx.x * blockDim.x + threadIdx.x;
    const float* in; unsigned short* out;
    if (i < 1048576)      { in = x;  out = xo; }
    else if (i < 1835008) { in = w1; out = w1o; i -= 1048576; }
    else                  { in = wp; out = wpo; i -= 1835008; }
    float4v v = *(const float4v*)(in + (size_t)i * 4);
    ushort4v o;
    o[0] = f2bf(v[0]); o[1] = f2bf(v[1]); o[2] = f2bf(v[2]); o[3] = f2bf(v[3]);
    *(ushort4v*)(out + (size_t)i * 4) = o;
}

// ---------------- GEMM1: qkv = x @ qkv_w^T + b : 256x192 tile, grid 16x16 = 256 ----------------
// R14/R16-verified (best measured qkv): 12 waves (4M x 3N), BK=64, LDS 112KB dbuf,
// wave-specialized staging (waves 0-7 stage A = 4 loads, waves 8-11 stage B = 6 loads)
// with exact counted vmcnt(4)/vmcnt(6). Per-region fragment epilogue:
// Q -> [B,H,N,D] coalesced; K -> kfrag PRE-SCALED (incl LOG2E); V -> vfrag.
__global__ __launch_bounds__(768, 3) void gemm_qkv(
    const unsigned short* __restrict__ A,   // x_bf  [4096][1024]
    const unsigned short* __restrict__ Bw,  // w1_bf [3072][1024]
    const float* __restrict__ bias,         // qkv_b [3072]
    const float* __restrict__ ps,           // phase_signal [2]
    const float* __restrict__ pw,           // phase_weight [16]
    unsigned short* __restrict__ qb,        // [B,H,N,D]
    unsigned short* __restrict__ kfrag,     // [bh][32][8][64][8]  (pre-scaled)
    unsigned short* __restrict__ vfrag)     // [bh][32][8][64][8]
{
    __shared__ unsigned short smem[57344];  // 112 KB
    unsigned short* As = smem;
    unsigned short* Bs = smem + 32768;

    const int tid = threadIdx.x;
    const int wid = tid >> 6;
    const int lane = tid & 63;
    const int l15 = lane & 15, l4 = lane >> 4;
    const int wave_n = wid >> 2;
    const int wave_m = wid & 3;

    const int bm = blockIdx.x;
    const int bn = blockIdx.y;

    f32x4 acc[4][4];
    const f32x4 zero4 = {0.f, 0.f, 0.f, 0.f};
#pragma unroll
    for (int m = 0; m < 4; ++m)
#pragma unroll
        for (int n = 0; n < 4; ++n) acc[m][n] = zero4;

    const int jr = lane >> 3;
    const int jc = ((lane & 7) ^ jr) << 4;
    const char* aB = (const char*)A  + (size_t)(bm * 256) * 2048;
    const char* bB = (const char*)Bw + (size_t)(bn * 192) * 2048;

    auto stage = [&](int t) {
        const int buf = t & 1;
        const size_t kb = (size_t)t * 128;
        if (wid < 8) {
#pragma unroll
            for (int i = 0; i < 4; ++i) {
                const int s = wid * 4 + i;
                gload_lds16(aB + (size_t)(s * 8 + jr) * 2048 + kb + jc,
                            (char*)(As + buf * 16384) + s * 1024);
            }
        } else {
#pragma unroll
            for (int i = 0; i < 6; ++i) {
                const int s = (wid - 8) * 6 + i;
                gload_lds16(bB + (size_t)(s * 8 + jr) * 2048 + kb + jc,
                            (char*)(Bs + buf * 12288) + s * 1024);
            }
        }
    };

    const int swz = (l15 & 7) << 4;

    stage(0); stage(1);
    if (wid < 8) { asm volatile("s_waitcnt vmcnt(4)" ::: "memory"); }
    else         { asm volatile("s_waitcnt vmcnt(6)" ::: "memory"); }
    __builtin_amdgcn_s_barrier();

    for (int t = 0; t < 16; ++t) {
        const int buf = t & 1;
        __builtin_amdgcn_s_setprio(1);
#pragma unroll
        for (int kk = 0; kk < 2; ++kk) {
            short8 a[4], b[4];
#pragma unroll
            for (int m = 0; m < 4; ++m)
                a[m] = *(const short8*)((const char*)(As + buf * 16384) +
                        (wave_m * 64 + m * 16 + l15) * 128 + ((kk * 64 + l4 * 16) ^ swz));
#pragma unroll
            for (int n = 0; n < 4; ++n)
                b[n] = *(const short8*)((const char*)(Bs + buf * 12288) +
                        (wave_n * 64 + n * 16 + l15) * 128 + ((kk * 64 + l4 * 16) ^ swz));
#pragma unroll
            for (int m = 0; m < 4; ++m)
#pragma unroll
                for (int n = 0; n < 4; ++n)
                    acc[m][n] = __builtin_amdgcn_mfma_f32_16x16x32_bf16(a[m], b[n], acc[m][n], 0, 0, 0);
        }
        __builtin_amdgcn_s_setprio(0);
        asm volatile("s_waitcnt lgkmcnt(0)" ::: "memory");  // own LDS reads retired
        __builtin_amdgcn_s_barrier();                       // all waves' reads retired
        if (t < 14) {
            stage(t + 2);                                   // restage live buffer (now safe)
            if (wid < 8) { asm volatile("s_waitcnt vmcnt(4)" ::: "memory"); }
            else         { asm volatile("s_waitcnt vmcnt(6)" ::: "memory"); }
        } else if (t == 14) {
            asm volatile("s_waitcnt vmcnt(0)" ::: "memory");
        }
        __builtin_amdgcn_s_barrier();
    }

    // ---------------- epilogue: per-region re-layout through LDS (R12/R14-verified) ----------------
    __syncthreads();
    char* tbc = (char*)smem;
    const int bb = bm >> 3;
    const int cb = bn * 192 + wave_n * 64;
    const int t3w = cb >> 10;
    const int hh_w = (cb >> 6) & 15;
    float kf = 1.f;
    if (t3w == 1)
        kf = 0.125f * LOG2E * (1.f + 0.2f * pw[hh_w] * ((bb == 0) ? ps[0] : ps[1]));

    if (t3w == 0) {
#pragma unroll
        for (int n = 0; n < 4; ++n) {
            const int d = n * 16 + l15;
            const float bv = bias[cb + n * 16 + l15];
#pragma unroll
            for (int m = 0; m < 4; ++m)
#pragma unroll
                for (int r = 0; r < 4; ++r) {
                    const int tt = wave_m * 64 + m * 16 + l4 * 4 + r;
                    *(unsigned short*)(tbc + wave_n * 32768 + tt * 128 +
                                       ((d * 2) ^ ((tt & 7) << 4))) = f2bf(acc[m][n][r] + bv);
                }
        }
    } else if (t3w == 1) {
#pragma unroll
        for (int n = 0; n < 4; ++n) {
            const int hi_ = l15 >> 3, e = l15 & 7;
            const float bv = bias[cb + n * 16 + l15];
#pragma unroll
            for (int m = 0; m < 4; ++m)
#pragma unroll
                for (int r = 0; r < 4; ++r) {
                    const int tt = wave_m * 64 + m * 16 + l4 * 4 + r;
                    const int T_ = tt >> 6, u = tt & 63;
                    const int s_ = u >> 5, l31_ = u & 31;
                    *(unsigned short*)(tbc + wave_n * 32768 + ((T_ * 8 + s_ * 4 + n) << 10) +
                                       ((hi_ * 32 + l31_) << 4) + e * 2) =
                        f2bf((acc[m][n][r] + bv) * kf);
                }
        }
    } else {
#pragma unroll
        for (int n = 0; n < 4; ++n) {
            const int dt_ = n >> 1;
            const int l31v = (n & 1) * 16 + l15;
            const float bv = bias[cb + n * 16 + l15];
#pragma unroll
            for (int m = 0; m < 4; ++m)
#pragma unroll
                for (int r = 0; r < 4; ++r) {
                    const int tt = wave_m * 64 + m * 16 + l4 * 4 + r;
                    const int T_ = tt >> 6, u = tt & 63;
                    const int ks = u >> 4, hi_ = (u >> 3) & 1, e = u & 7;
                    *(unsigned short*)(tbc + wave_n * 32768 + ((T_ * 8 + dt_ * 4 + ks) << 10) +
                                       ((hi_ * 32 + l31v) << 4) + e * 2) =
                        f2bf(acc[m][n][r] + bv);
                }
        }
    }
    __syncthreads();

#pragma unroll
    for (int i = 0; i < 8; ++i) {
        const int flat = (i * 768 + tid) * 16;
        const int region = flat >> 15;
        const int cbr = bn * 192 + region * 64;
        const int t3r = cbr >> 10;
        const int hhr = (cbr >> 6) & 15;
        const int within = flat & 32767;
        if (t3r == 0) {
            const int tt = within >> 7;
            const int chunk = (within >> 4) & 7;
            const short8 v = *(const short8*)(tbc + region * 32768 + tt * 128 +
                                              ((chunk * 16) ^ ((tt & 7) << 4)));
            *(short8*)(qb + ((size_t)(bb * 16 + hhr) * 2048 + (bm & 7) * 256 + tt) * 64 +
                       chunk * 8) = v;
        } else {
            const int c2 = within >> 13;
            const int off = within & 8191;
            const short8 v = *(const short8*)(tbc + region * 32768 + c2 * 8192 + off);
            unsigned short* dstb = (t3r == 1) ? kfrag : vfrag;
            *(short8*)(dstb + ((size_t)(bb * 16 + hhr) * 32 + (bm & 7) * 4 + c2) * 4096 +
                       (off >> 1)) = v;
        }
    }
}

// ---------------- GEMM2: out = attn @ proj_w^T + b (fp32 out) ----------------
// STANDALONE (R8-verified): 128^2 2-phase dbuf, natural block order.
__global__ __launch_bounds__(256, 2) void gemm_proj(
    const unsigned short* __restrict__ A,   // attn_bf [4096][1024]
    const unsigned short* __restrict__ Bw,  // wp_bf   [1024][1024]
    const float* __restrict__ bias,         // proj_b  [1024]
    float* __restrict__ out)                // [4096][1024] fp32
{
    __shared__ unsigned short As[2][128 * 64];
    __shared__ unsigned short Bs[2][128 * 64];
    const int tid = threadIdx.x;
    const int wid = tid >> 6;
    const int lane = tid & 63;
    const int l15 = lane & 15, l4 = lane >> 4;
    const int bm = blockIdx.x, bn = blockIdx.y;
    const int wr = wid >> 1, wc = wid & 1;

    f32x4 acc[4][4];
    const f32x4 zero4 = {0.f, 0.f, 0.f, 0.f};
#pragma unroll
    for (int m = 0; m < 4; ++m)
#pragma unroll
        for (int n = 0; n < 4; ++n) acc[m][n] = zero4;

    const int jr = lane >> 3;
    const int jc = ((lane & 7) ^ jr) << 4;
    const char* aB = (const char*)A  + (size_t)(bm * 128) * 2048;
    const char* bB = (const char*)Bw + (size_t)(bn * 128) * 2048;

    auto stage = [&](int buf, int k0) {
#pragma unroll
        for (int i = 0; i < 4; ++i) {
            const int rowb = wid * 32 + i * 8;
            gload_lds16(aB + (size_t)(rowb + jr) * 2048 + k0 * 2 + jc,
                        (const char*)&As[buf][0] + rowb * 128);
            gload_lds16(bB + (size_t)(rowb + jr) * 2048 + k0 * 2 + jc,
                        (const char*)&Bs[buf][0] + rowb * 128);
        }
    };

    const int swz = (l15 & 7) << 4;

    stage(0, 0);
    for (int it = 0; it < 16; ++it) {
        const int buf = it & 1;
        __syncthreads();
        if (it < 15) stage(buf ^ 1, (it + 1) * 64);
#pragma unroll
        for (int kk = 0; kk < 2; ++kk) {
            short8 a[4], b[4];
#pragma unroll
            for (int m = 0; m < 4; ++m)
                a[m] = *(const short8*)((const char*)&As[buf][0] +
                        (wr * 64 + m * 16 + l15) * 128 + ((kk * 64 + l4 * 16) ^ swz));
#pragma unroll
            for (int n = 0; n < 4; ++n)
                b[n] = *(const short8*)((const char*)&Bs[buf][0] +
                        (wc * 64 + n * 16 + l15) * 128 + ((kk * 64 + l4 * 16) ^ swz));
            __builtin_amdgcn_s_setprio(1);
#pragma unroll
            for (int m = 0; m < 4; ++m)
#pragma unroll
                for (int n = 0; n < 4; ++n)
                    acc[m][n] = __builtin_amdgcn_mfma_f32_16x16x32_bf16(a[m], b[n], acc[m][n], 0, 0, 0);
            __builtin_amdgcn_s_setprio(0);
        }
    }

    const int row_base = bm * 128 + wr * 64;
    const int col_base = bn * 128 + wc * 64;
#pragma unroll
    for (int n = 0; n < 4; ++n) {
        const int col = col_base + n * 16 + l15;
        const float bv = bias[col];
#pragma unroll
        for (int m = 0; m < 4; ++m) {
#pragma unroll
            for (int r = 0; r < 4; ++r) {
                const int row = row_base + m * 16 + l4 * 4 + r;
                out[(size_t)row * 1024 + col] = acc[m][n][r] + bv;
            }
        }
    }
}

// ---------------- Flash attention: non-split, 3-deep counted pipeline ----------------
// R16-verified structure. CHANGE (ILP): split accumulators — oacc[s][dt] (4 accs,
// 2 dep MFMA/iter each) and lacc[s] (2 accs) summed in the epilogue. MFMA count
// unchanged; per-iter serial accumulate chain 256->64 cyc (latency-bound relief,
// grid-capped occupancy means TLP can't help). +48 VGPR, still 4 waves/SIMD.
__global__ __launch_bounds__(256, 2) void attn_kernel(
    const unsigned short* __restrict__ qb,     // [B,H,N,D]
    const unsigned short* __restrict__ kfrag,  // [bh][32][8][64][8] pre-scaled
    const unsigned short* __restrict__ vfrag,  // [bh][32][8][64][8]
    unsigned short* __restrict__ aout)         // [B*N][C] bf16
{
    __shared__ unsigned short KVs[3][2][4096];   // 48 KB, 3-deep

    const int tid = threadIdx.x;
    const int w = tid >> 6;
    const int l = tid & 63;
    const int l31 = l & 31;
    const int hi = l >> 5;

    // T1: bijective XCD remap (nwg=512, 64/XCD)
    const int bid = blockIdx.y * 16 + blockIdx.x;
    const int wg = (bid & 7) * 64 + (bid >> 3);
    const int bh = wg >> 4;
    const int b = bh >> 4, h = bh & 15;
    const int q0 = (wg & 15) * 128 + w * 32;

    const char* qg = (const char*)(qb + (size_t)bh * 2048 * 64);
    const unsigned short* kg = kfrag + (size_t)bh * 32 * 4096;
    const unsigned short* vg = vfrag + (size_t)bh * 32 * 4096;

    short8 qf[4];
#pragma unroll
    for (int t = 0; t < 4; ++t)
        qf[t] = *(const short8*)(qg + (size_t)(q0 + l31) * 128 + t * 32 + hi * 16);

    short8 ones;
#pragma unroll
    for (int j = 0; j < 8; ++j) ones[j] = (short)0x3F80;   // bf16 1.0

    f32x16 oacc[2][2], lacc[2];
#pragma unroll
    for (int r = 0; r < 16; ++r) {
        oacc[0][0][r] = 0.f; oacc[0][1][r] = 0.f;
        oacc[1][0][r] = 0.f; oacc[1][1][r] = 0.f;
        lacc[0][r] = 0.f; lacc[1][r] = 0.f;
    }

    auto stage = [&](int buf, int T) {
#pragma unroll
        for (int i = 0; i < 2; ++i) {
            const int c = w * 2 + i;
            gload_lds16(kg + (size_t)T * 4096 + c * 512 + l * 8, &KVs[buf][0][c * 512]);
            gload_lds16(vg + (size_t)T * 4096 + c * 512 + l * 8, &KVs[buf][1][c * 512]);
        }
    };

    // prologue: tiles 0,1; vmcnt(4) = tile 0's 4 loads (oldest) landed
    stage(0, 0); stage(1, 1);
    asm volatile("s_waitcnt vmcnt(4)" ::: "memory");
    __builtin_amdgcn_s_barrier();

    int buf = 0;
    for (int it = 0; it < 32; ++it) {
        int nxt2 = buf + 2; if (nxt2 >= 3) nxt2 -= 3;
        if (it < 30) stage(nxt2, it + 2);

        const unsigned short* Kb = &KVs[buf][0][0];
        const unsigned short* Vb = &KVs[buf][1][0];

        // S^T = K.Q^T : lane holds q=l&31, 32 kv values across sa[0..1]
        f32x16 sa[2];
        __builtin_amdgcn_s_setprio(1);
#pragma unroll
        for (int s = 0; s < 2; ++s) {
#pragma unroll
            for (int r = 0; r < 16; ++r) sa[s][r] = 0.f;
#pragma unroll
            for (int t = 0; t < 4; ++t) {
                const short8 kf = *(const short8*)(Kb + (s * 4 + t) * 512 + l * 8);
                sa[s] = __builtin_amdgcn_mfma_f32_32x32x16_bf16(kf, qf[t], sa[s], 0, 0, 0);
            }
        }
        __builtin_amdgcn_s_setprio(0);

        // P = 2^s (uniform scale cancels in O/lr)
#pragma unroll
        for (int s = 0; s < 2; ++s)
#pragma unroll
            for (int r = 0; r < 16; ++r)
                sa[s][r] = __builtin_amdgcn_exp2f(sa[s][r]);

        // P -> bf16 B-fragments; PV + MFMA-rowsum into SPLIT accumulators
#pragma unroll
        for (int s = 0; s < 2; ++s) {
            unsigned int wv[8];
#pragma unroll
            for (int g = 0; g < 8; ++g)
                wv[g] = cvtpk(sa[s][g * 2], sa[s][g * 2 + 1]);
            plswap(wv[0], wv[2]); plswap(wv[1], wv[3]);
            plswap(wv[4], wv[6]); plswap(wv[5], wv[7]);
            union { unsigned int u[4]; short8 s8; } f0, f1;
            f0.u[0] = wv[0]; f0.u[1] = wv[1]; f0.u[2] = wv[2]; f0.u[3] = wv[3];
            f1.u[0] = wv[4]; f1.u[1] = wv[5]; f1.u[2] = wv[6]; f1.u[3] = wv[7];
            __builtin_amdgcn_s_setprio(1);
            lacc[s] = __builtin_amdgcn_mfma_f32_32x32x16_bf16(ones, f0.s8, lacc[s], 0, 0, 0);
            lacc[s] = __builtin_amdgcn_mfma_f32_32x32x16_bf16(ones, f1.s8, lacc[s], 0, 0, 0);
#pragma unroll
            for (int dt = 0; dt < 2; ++dt) {
                const short8 v0 = *(const short8*)(Vb + (dt * 4 + s * 2 + 0) * 512 + l * 8);
                oacc[s][dt] = __builtin_amdgcn_mfma_f32_32x32x16_bf16(v0, f0.s8, oacc[s][dt], 0, 0, 0);
                const short8 v1 = *(const short8*)(Vb + (dt * 4 + s * 2 + 1) * 512 + l * 8);
                oacc[s][dt] = __builtin_amdgcn_mfma_f32_32x32x16_bf16(v1, f1.s8, oacc[s][dt], 0, 0, 0);
            }
            __builtin_amdgcn_s_setprio(0);
        }

        // pipeline control: tile it+1 landed (counted, never 0 mid-loop);
        // lgkmcnt(0)+barrier retire this buf's reads before next iter re-stages it
        if (it < 30) {
            asm volatile("s_waitcnt vmcnt(4) lgkmcnt(0)" ::: "memory");
            __builtin_amdgcn_s_barrier();
        } else if (it == 30) {
            asm volatile("s_waitcnt vmcnt(0) lgkmcnt(0)" ::: "memory");
            __builtin_amdgcn_s_barrier();
        }
        ++buf; if (buf >= 3) buf -= 3;
    }

    // epilogue: O = (oacc0+oacc1)/(lacc0+lacc1)
    const float inv = 1.0f / (lacc[0][0] + lacc[1][0]);
    char* outp = (char*)aout + ((size_t)(b * 2048 + q0 + l31) * 1024 + h * 64) * 2;
#pragma unroll
    for (int dt = 0; dt < 2; ++dt)
#pragma unroll
        for (int rg = 0; rg < 4; ++rg) {
            u32x2 pkd;
            pkd[0] = cvtpk((oacc[0][dt][rg * 4 + 0] + oacc[1][dt][rg * 4 + 0]) * inv,
                           (oacc[0][dt][rg * 4 + 1] + oacc[1][dt][rg * 4 + 1]) * inv);
            pkd[1] = cvtpk((oacc[0][dt][rg * 4 + 2] + oacc[1][dt][rg * 4 + 2]) * inv,
                           (oacc[0][dt][rg * 4 + 3] + oacc[1][dt][rg * 4 + 3]) * inv);
            *(u32x2*)(outp + (size_t)(dt * 32 + rg * 8 + hi * 4) * 2) = pkd;
        }
}

extern "C" void kernel_launch(void* const* d_in, const int* in_sizes, int n_in,
                              void* d_out, int out_size, void* d_ws, size_t ws_size,
                              hipStream_t stream) {
    const float* x      = (const float*)d_in[0];
    const float* ps     = (const float*)d_in[1];
    const float* qkv_w  = (const float*)d_in[2];
    const float* qkv_b  = (const float*)d_in[3];
    const float* proj_w = (const float*)d_in[4];
    const float* proj_b = (const float*)d_in[5];
    const float* pw     = (const float*)d_in[6];
    float* out = (float*)d_out;
    char* ws = (char*)d_ws;

    unsigned short* x_bf    = (unsigned short*)(ws);                   // 8 MB (reused: attn_bf)
    unsigned short* w1_bf   = (unsigned short*)(ws + (8u  << 20));     // 6 MB
    unsigned short* wp_bf   = (unsigned short*)(ws + (14u << 20));     // 2 MB
    unsigned short* qb      = (unsigned short*)(ws + (16u << 20));     // 8 MB
    unsigned short* kfrag   = (unsigned short*)(ws + (24u << 20));     // 8 MB
    unsigned short* vfrag   = (unsigned short*)(ws + (32u << 20));     // 8 MB
    unsigned short* attn_bf = x_bf;                                    // x_bf dead after gemm_qkv

    cvt_all_kernel<<<8192, 256, 0, stream>>>(x, qkv_w, proj_w, x_bf, w1_bf, wp_bf);
    gemm_qkv<<<dim3(16, 16), 768, 0, stream>>>(x_bf, w1_bf, qkv_b, ps, pw, qb, kfrag, vfrag);
    attn_kernel<<<dim3(16, 32), 256, 0, stream>>>(qb, kfrag, vfrag, attn_bf);
    gemm_proj<<<dim3(32, 8), 256, 0, stream>>>(attn_bf, wp_bf, proj_b, out);
}

// Round 18
// 102.152 us; speedup vs baseline: 1.0114x; 1.0114x over previous
//
#include <hip/hip_runtime.h>
#include <stdint.h>

#define NUM_H 16
#define HD    64
#define CDIM  1024
#define NSEQ  2048
#define NBATCH 2
#define LOG2E 1.4426950408889634f

typedef __attribute__((ext_vector_type(8))) short short8;
typedef __attribute__((ext_vector_type(4))) float f32x4;
typedef __attribute__((ext_vector_type(16))) float f32x16;
typedef __attribute__((ext_vector_type(4))) unsigned short ushort4v;
typedef __attribute__((ext_vector_type(4))) float float4v;
typedef __attribute__((ext_vector_type(2))) unsigned int u32x2;

__device__ __forceinline__ unsigned short f2bf(float f) {
    unsigned int u = __builtin_bit_cast(unsigned int, f);
    unsigned int r = u + 0x7fffu + ((u >> 16) & 1u);
    return (unsigned short)(r >> 16);
}

__device__ __forceinline__ unsigned int cvtpk(float a, float b) {
    unsigned int r;
    asm("v_cvt_pk_bf16_f32 %0, %1, %2" : "=v"(r) : "v"(a), "v"(b));
    return r;
}

__device__ __forceinline__ void plswap(unsigned int &a, unsigned int &b) {
    asm("v_permlane32_swap_b32 %0, %1" : "+v"(a), "+v"(b));
}

// global -> LDS async copy, 16B per lane. LDS dest is wave-uniform base + lane*16.
__device__ __forceinline__ void gload_lds16(const void* g, const void* l) {
    __builtin_amdgcn_global_load_lds(
        (const __attribute__((address_space(1))) unsigned int*)(unsigned long long)(uintptr_t)g,
        (__attribute__((address_space(3))) unsigned int*)(unsigned int)(uintptr_t)l,
        16, 0, 0);
}

// fused fp32->bf16 convert for x, qkv_w, proj_w (one launch)
__global__ void cvt_all_kernel(const float* __restrict__ x,
                               const float* __restrict__ w1,
                               const float* __restrict__ wp,
                               unsigned short* __restrict__ xo,
                               unsigned short* __restrict__ w1o,
                               unsigned short* __restrict__ wpo) {
    int i = blockIdx.x * blockDim.x + threadIdx.x;
    const float* in; unsigned short* out;
    if (i < 1048576)      { in = x;  out = xo; }
    else if (i < 1835008) { in = w1; out = w1o; i -= 1048576; }
    else                  { in = wp; out = wpo; i -= 1835008; }
    float4v v = *(const float4v*)(in + (size_t)i * 4);
    ushort4v o;
    o[0] = f2bf(v[0]); o[1] = f2bf(v[1]); o[2] = f2bf(v[2]); o[3] = f2bf(v[3]);
    *(ushort4v*)(out + (size_t)i * 4) = o;
}

// ---------------- GEMM1: qkv = x @ qkv_w^T + b : 256x192 tile, grid 16x16 = 256 ----------------
// R14/R16-verified (best measured qkv): 12 waves (4M x 3N), BK=64, LDS 112KB dbuf,
// wave-specialized staging (waves 0-7 stage A = 4 loads, waves 8-11 stage B = 6 loads)
// with exact counted vmcnt(4)/vmcnt(6). Per-region fragment epilogue:
// Q -> [B,H,N,D] coalesced; K -> kfrag PRE-SCALED (incl LOG2E); V -> vfrag.
__global__ __launch_bounds__(768, 3) void gemm_qkv(
    const unsigned short* __restrict__ A,   // x_bf  [4096][1024]
    const unsigned short* __restrict__ Bw,  // w1_bf [3072][1024]
    const float* __restrict__ bias,         // qkv_b [3072]
    const float* __restrict__ ps,           // phase_signal [2]
    const float* __restrict__ pw,           // phase_weight [16]
    unsigned short* __restrict__ qb,        // [B,H,N,D]
    unsigned short* __restrict__ kfrag,     // [bh][32][8][64][8]  (pre-scaled)
    unsigned short* __restrict__ vfrag)     // [bh][32][8][64][8]
{
    __shared__ unsigned short smem[57344];  // 112 KB
    unsigned short* As = smem;
    unsigned short* Bs = smem + 32768;

    const int tid = threadIdx.x;
    const int wid = tid >> 6;
    const int lane = tid & 63;
    const int l15 = lane & 15, l4 = lane >> 4;
    const int wave_n = wid >> 2;
    const int wave_m = wid & 3;

    const int bm = blockIdx.x;
    const int bn = blockIdx.y;

    f32x4 acc[4][4];
    const f32x4 zero4 = {0.f, 0.f, 0.f, 0.f};
#pragma unroll
    for (int m = 0; m < 4; ++m)
#pragma unroll
        for (int n = 0; n < 4; ++n) acc[m][n] = zero4;

    const int jr = lane >> 3;
    const int jc = ((lane & 7) ^ jr) << 4;
    const char* aB = (const char*)A  + (size_t)(bm * 256) * 2048;
    const char* bB = (const char*)Bw + (size_t)(bn * 192) * 2048;

    auto stage = [&](int t) {
        const int buf = t & 1;
        const size_t kb = (size_t)t * 128;
        if (wid < 8) {
#pragma unroll
            for (int i = 0; i < 4; ++i) {
                const int s = wid * 4 + i;
                gload_lds16(aB + (size_t)(s * 8 + jr) * 2048 + kb + jc,
                            (char*)(As + buf * 16384) + s * 1024);
            }
        } else {
#pragma unroll
            for (int i = 0; i < 6; ++i) {
                const int s = (wid - 8) * 6 + i;
                gload_lds16(bB + (size_t)(s * 8 + jr) * 2048 + kb + jc,
                            (char*)(Bs + buf * 12288) + s * 1024);
            }
        }
    };

    const int swz = (l15 & 7) << 4;

    stage(0); stage(1);
    if (wid < 8) { asm volatile("s_waitcnt vmcnt(4)" ::: "memory"); }
    else         { asm volatile("s_waitcnt vmcnt(6)" ::: "memory"); }
    __builtin_amdgcn_s_barrier();

    for (int t = 0; t < 16; ++t) {
        const int buf = t & 1;
        __builtin_amdgcn_s_setprio(1);
#pragma unroll
        for (int kk = 0; kk < 2; ++kk) {
            short8 a[4], b[4];
#pragma unroll
            for (int m = 0; m < 4; ++m)
                a[m] = *(const short8*)((const char*)(As + buf * 16384) +
                        (wave_m * 64 + m * 16 + l15) * 128 + ((kk * 64 + l4 * 16) ^ swz));
#pragma unroll
            for (int n = 0; n < 4; ++n)
                b[n] = *(const short8*)((const char*)(Bs + buf * 12288) +
                        (wave_n * 64 + n * 16 + l15) * 128 + ((kk * 64 + l4 * 16) ^ swz));
#pragma unroll
            for (int m = 0; m < 4; ++m)
#pragma unroll
                for (int n = 0; n < 4; ++n)
                    acc[m][n] = __builtin_amdgcn_mfma_f32_16x16x32_bf16(a[m], b[n], acc[m][n], 0, 0, 0);
        }
        __builtin_amdgcn_s_setprio(0);
        asm volatile("s_waitcnt lgkmcnt(0)" ::: "memory");  // own LDS reads retired
        __builtin_amdgcn_s_barrier();                       // all waves' reads retired
        if (t < 14) {
            stage(t + 2);                                   // restage live buffer (now safe)
            if (wid < 8) { asm volatile("s_waitcnt vmcnt(4)" ::: "memory"); }
            else         { asm volatile("s_waitcnt vmcnt(6)" ::: "memory"); }
        } else if (t == 14) {
            asm volatile("s_waitcnt vmcnt(0)" ::: "memory");
        }
        __builtin_amdgcn_s_barrier();
    }

    // ---------------- epilogue: per-region re-layout through LDS (R12/R14-verified) ----------------
    __syncthreads();
    char* tbc = (char*)smem;
    const int bb = bm >> 3;
    const int cb = bn * 192 + wave_n * 64;
    const int t3w = cb >> 10;
    const int hh_w = (cb >> 6) & 15;
    float kf = 1.f;
    if (t3w == 1)
        kf = 0.125f * LOG2E * (1.f + 0.2f * pw[hh_w] * ((bb == 0) ? ps[0] : ps[1]));

    if (t3w == 0) {
#pragma unroll
        for (int n = 0; n < 4; ++n) {
            const int d = n * 16 + l15;
            const float bv = bias[cb + n * 16 + l15];
#pragma unroll
            for (int m = 0; m < 4; ++m)
#pragma unroll
                for (int r = 0; r < 4; ++r) {
                    const int tt = wave_m * 64 + m * 16 + l4 * 4 + r;
                    *(unsigned short*)(tbc + wave_n * 32768 + tt * 128 +
                                       ((d * 2) ^ ((tt & 7) << 4))) = f2bf(acc[m][n][r] + bv);
                }
        }
    } else if (t3w == 1) {
#pragma unroll
        for (int n = 0; n < 4; ++n) {
            const int hi_ = l15 >> 3, e = l15 & 7;
            const float bv = bias[cb + n * 16 + l15];
#pragma unroll
            for (int m = 0; m < 4; ++m)
#pragma unroll
                for (int r = 0; r < 4; ++r) {
                    const int tt = wave_m * 64 + m * 16 + l4 * 4 + r;
                    const int T_ = tt >> 6, u = tt & 63;
                    const int s_ = u >> 5, l31_ = u & 31;
                    *(unsigned short*)(tbc + wave_n * 32768 + ((T_ * 8 + s_ * 4 + n) << 10) +
                                       ((hi_ * 32 + l31_) << 4) + e * 2) =
                        f2bf((acc[m][n][r] + bv) * kf);
                }
        }
    } else {
#pragma unroll
        for (int n = 0; n < 4; ++n) {
            const int dt_ = n >> 1;
            const int l31v = (n & 1) * 16 + l15;
            const float bv = bias[cb + n * 16 + l15];
#pragma unroll
            for (int m = 0; m < 4; ++m)
#pragma unroll
                for (int r = 0; r < 4; ++r) {
                    const int tt = wave_m * 64 + m * 16 + l4 * 4 + r;
                    const int T_ = tt >> 6, u = tt & 63;
                    const int ks = u >> 4, hi_ = (u >> 3) & 1, e = u & 7;
                    *(unsigned short*)(tbc + wave_n * 32768 + ((T_ * 8 + dt_ * 4 + ks) << 10) +
                                       ((hi_ * 32 + l31v) << 4) + e * 2) =
                        f2bf(acc[m][n][r] + bv);
                }
        }
    }
    __syncthreads();

#pragma unroll
    for (int i = 0; i < 8; ++i) {
        const int flat = (i * 768 + tid) * 16;
        const int region = flat >> 15;
        const int cbr = bn * 192 + region * 64;
        const int t3r = cbr >> 10;
        const int hhr = (cbr >> 6) & 15;
        const int within = flat & 32767;
        if (t3r == 0) {
            const int tt = within >> 7;
            const int chunk = (within >> 4) & 7;
            const short8 v = *(const short8*)(tbc + region * 32768 + tt * 128 +
                                              ((chunk * 16) ^ ((tt & 7) << 4)));
            *(short8*)(qb + ((size_t)(bb * 16 + hhr) * 2048 + (bm & 7) * 256 + tt) * 64 +
                       chunk * 8) = v;
        } else {
            const int c2 = within >> 13;
            const int off = within & 8191;
            const short8 v = *(const short8*)(tbc + region * 32768 + c2 * 8192 + off);
            unsigned short* dstb = (t3r == 1) ? kfrag : vfrag;
            *(short8*)(dstb + ((size_t)(bb * 16 + hhr) * 32 + (bm & 7) * 4 + c2) * 4096 +
                       (off >> 1)) = v;
        }
    }
}

// ---------------- GEMM2: out = attn @ proj_w^T + b (fp32 out) ----------------
// STANDALONE (R8-verified): 128^2 2-phase dbuf, natural block order.
__global__ __launch_bounds__(256, 2) void gemm_proj(
    const unsigned short* __restrict__ A,   // attn_bf [4096][1024]
    const unsigned short* __restrict__ Bw,  // wp_bf   [1024][1024]
    const float* __restrict__ bias,         // proj_b  [1024]
    float* __restrict__ out)                // [4096][1024] fp32
{
    __shared__ unsigned short As[2][128 * 64];
    __shared__ unsigned short Bs[2][128 * 64];
    const int tid = threadIdx.x;
    const int wid = tid >> 6;
    const int lane = tid & 63;
    const int l15 = lane & 15, l4 = lane >> 4;
    const int bm = blockIdx.x, bn = blockIdx.y;
    const int wr = wid >> 1, wc = wid & 1;

    f32x4 acc[4][4];
    const f32x4 zero4 = {0.f, 0.f, 0.f, 0.f};
#pragma unroll
    for (int m = 0; m < 4; ++m)
#pragma unroll
        for (int n = 0; n < 4; ++n) acc[m][n] = zero4;

    const int jr = lane >> 3;
    const int jc = ((lane & 7) ^ jr) << 4;
    const char* aB = (const char*)A  + (size_t)(bm * 128) * 2048;
    const char* bB = (const char*)Bw + (size_t)(bn * 128) * 2048;

    auto stage = [&](int buf, int k0) {
#pragma unroll
        for (int i = 0; i < 4; ++i) {
            const int rowb = wid * 32 + i * 8;
            gload_lds16(aB + (size_t)(rowb + jr) * 2048 + k0 * 2 + jc,
                        (const char*)&As[buf][0] + rowb * 128);
            gload_lds16(bB + (size_t)(rowb + jr) * 2048 + k0 * 2 + jc,
                        (const char*)&Bs[buf][0] + rowb * 128);
        }
    };

    const int swz = (l15 & 7) << 4;

    stage(0, 0);
    for (int it = 0; it < 16; ++it) {
        const int buf = it & 1;
        __syncthreads();
        if (it < 15) stage(buf ^ 1, (it + 1) * 64);
#pragma unroll
        for (int kk = 0; kk < 2; ++kk) {
            short8 a[4], b[4];
#pragma unroll
            for (int m = 0; m < 4; ++m)
                a[m] = *(const short8*)((const char*)&As[buf][0] +
                        (wr * 64 + m * 16 + l15) * 128 + ((kk * 64 + l4 * 16) ^ swz));
#pragma unroll
            for (int n = 0; n < 4; ++n)
                b[n] = *(const short8*)((const char*)&Bs[buf][0] +
                        (wc * 64 + n * 16 + l15) * 128 + ((kk * 64 + l4 * 16) ^ swz));
            __builtin_amdgcn_s_setprio(1);
#pragma unroll
            for (int m = 0; m < 4; ++m)
#pragma unroll
                for (int n = 0; n < 4; ++n)
                    acc[m][n] = __builtin_amdgcn_mfma_f32_16x16x32_bf16(a[m], b[n], acc[m][n], 0, 0, 0);
            __builtin_amdgcn_s_setprio(0);
        }
    }

    const int row_base = bm * 128 + wr * 64;
    const int col_base = bn * 128 + wc * 64;
#pragma unroll
    for (int n = 0; n < 4; ++n) {
        const int col = col_base + n * 16 + l15;
        const float bv = bias[col];
#pragma unroll
        for (int m = 0; m < 4; ++m) {
#pragma unroll
            for (int r = 0; r < 4; ++r) {
                const int row = row_base + m * 16 + l4 * 4 + r;
                out[(size_t)row * 1024 + col] = acc[m][n][r] + bv;
            }
        }
    }
}

// ---------------- Flash attention: non-split, 2-TILE CHUNKS, 2-deep counted pipeline ----------------
// CHANGE vs R16: process 2 KV tiles per barrier interval (16 chunk-iters). Tile B's
// QK^T overlaps tile A's exp2/cvtpk/PV (cross-tile ILP at UNCHANGED occupancy —
// LDS 64KB chunks x 2-deep, still 2 blocks/CU; barriers halve 62->30).
// Ledger: compute chunk c from buf c&1 -> lgkm(0)+barrier (reads retired) ->
// restage same buf with chunk c+2 (8 loads/wave) -> vmcnt(8) = chunk c+1 landed
// (issued one full compute phase ago) -> barrier. P = 2^s direct (R15-verified).
__global__ __launch_bounds__(256, 2) void attn_kernel(
    const unsigned short* __restrict__ qb,     // [B,H,N,D]
    const unsigned short* __restrict__ kfrag,  // [bh][32][8][64][8] pre-scaled
    const unsigned short* __restrict__ vfrag,  // [bh][32][8][64][8]
    unsigned short* __restrict__ aout)         // [B*N][C] bf16
{
    __shared__ unsigned short KVs[2][2][2][4096];   // [buf][tile][K/V][frags] = 64 KB

    const int tid = threadIdx.x;
    const int w = tid >> 6;
    const int l = tid & 63;
    const int l31 = l & 31;
    const int hi = l >> 5;

    // T1: bijective XCD remap (nwg=512, 64/XCD)
    const int bid = blockIdx.y * 16 + blockIdx.x;
    const int wg = (bid & 7) * 64 + (bid >> 3);
    const int bh = wg >> 4;
    const int b = bh >> 4, h = bh & 15;
    const int q0 = (wg & 15) * 128 + w * 32;

    const char* qg = (const char*)(qb + (size_t)bh * 2048 * 64);
    const unsigned short* kg = kfrag + (size_t)bh * 32 * 4096;
    const unsigned short* vg = vfrag + (size_t)bh * 32 * 4096;

    short8 qf[4];
#pragma unroll
    for (int t = 0; t < 4; ++t)
        qf[t] = *(const short8*)(qg + (size_t)(q0 + l31) * 128 + t * 32 + hi * 16);

    short8 ones;
#pragma unroll
    for (int j = 0; j < 8; ++j) ones[j] = (short)0x3F80;   // bf16 1.0

    f32x16 oacc[2], lacc;
#pragma unroll
    for (int r = 0; r < 16; ++r) { oacc[0][r] = 0.f; oacc[1][r] = 0.f; lacc[r] = 0.f; }

    // stage chunk c (tiles 2c, 2c+1) into buf: 8 loads/wave
    auto stage = [&](int buf, int c) {
#pragma unroll
        for (int ti = 0; ti < 2; ++ti)
#pragma unroll
            for (int i = 0; i < 2; ++i) {
                const int cc = w * 2 + i;
                gload_lds16(kg + (size_t)(2 * c + ti) * 4096 + cc * 512 + l * 8,
                            &KVs[buf][ti][0][cc * 512]);
                gload_lds16(vg + (size_t)(2 * c + ti) * 4096 + cc * 512 + l * 8,
                            &KVs[buf][ti][1][cc * 512]);
            }
    };

    // prologue: chunks 0,1; vmcnt(8) = chunk 0's 8 loads (oldest) landed
    stage(0, 0); stage(1, 1);
    asm volatile("s_waitcnt vmcnt(8)" ::: "memory");
    __builtin_amdgcn_s_barrier();

    for (int c = 0; c < 16; ++c) {
        const int buf = c & 1;
        const unsigned short* KbA = &KVs[buf][0][0][0];
        const unsigned short* VbA = &KVs[buf][0][1][0];
        const unsigned short* KbB = &KVs[buf][1][0][0];
        const unsigned short* VbB = &KVs[buf][1][1][0];

        // QK^T for BOTH tiles first (independent MFMA chains; B's overlap A's softmax)
        f32x16 saA[2], saB[2];
        __builtin_amdgcn_s_setprio(1);
#pragma unroll
        for (int s = 0; s < 2; ++s) {
#pragma unroll
            for (int r = 0; r < 16; ++r) saA[s][r] = 0.f;
#pragma unroll
            for (int t = 0; t < 4; ++t) {
                const short8 kf = *(const short8*)(KbA + (s * 4 + t) * 512 + l * 8);
                saA[s] = __builtin_amdgcn_mfma_f32_32x32x16_bf16(kf, qf[t], saA[s], 0, 0, 0);
            }
        }
#pragma unroll
        for (int s = 0; s < 2; ++s) {
#pragma unroll
            for (int r = 0; r < 16; ++r) saB[s][r] = 0.f;
#pragma unroll
            for (int t = 0; t < 4; ++t) {
                const short8 kf = *(const short8*)(KbB + (s * 4 + t) * 512 + l * 8);
                saB[s] = __builtin_amdgcn_mfma_f32_32x32x16_bf16(kf, qf[t], saB[s], 0, 0, 0);
            }
        }
        __builtin_amdgcn_s_setprio(0);

        // ---- tile A: softmax + PV
#pragma unroll
        for (int s = 0; s < 2; ++s)
#pragma unroll
            for (int r = 0; r < 16; ++r)
                saA[s][r] = __builtin_amdgcn_exp2f(saA[s][r]);
#pragma unroll
        for (int s = 0; s < 2; ++s) {
            unsigned int wv[8];
#pragma unroll
            for (int g = 0; g < 8; ++g)
                wv[g] = cvtpk(saA[s][g * 2], saA[s][g * 2 + 1]);
            plswap(wv[0], wv[2]); plswap(wv[1], wv[3]);
            plswap(wv[4], wv[6]); plswap(wv[5], wv[7]);
            union { unsigned int u[4]; short8 s8; } f0, f1;
            f0.u[0] = wv[0]; f0.u[1] = wv[1]; f0.u[2] = wv[2]; f0.u[3] = wv[3];
            f1.u[0] = wv[4]; f1.u[1] = wv[5]; f1.u[2] = wv[6]; f1.u[3] = wv[7];
            __builtin_amdgcn_s_setprio(1);
            lacc = __builtin_amdgcn_mfma_f32_32x32x16_bf16(ones, f0.s8, lacc, 0, 0, 0);
            lacc = __builtin_amdgcn_mfma_f32_32x32x16_bf16(ones, f1.s8, lacc, 0, 0, 0);
#pragma unroll
            for (int dt = 0; dt < 2; ++dt) {
                const short8 v0 = *(const short8*)(VbA + (dt * 4 + s * 2 + 0) * 512 + l * 8);
                oacc[dt] = __builtin_amdgcn_mfma_f32_32x32x16_bf16(v0, f0.s8, oacc[dt], 0, 0, 0);
                const short8 v1 = *(const short8*)(VbA + (dt * 4 + s * 2 + 1) * 512 + l * 8);
                oacc[dt] = __builtin_amdgcn_mfma_f32_32x32x16_bf16(v1, f1.s8, oacc[dt], 0, 0, 0);
            }
            __builtin_amdgcn_s_setprio(0);
        }

        // ---- tile B: softmax + PV
#pragma unroll
        for (int s = 0; s < 2; ++s)
#pragma unroll
            for (int r = 0; r < 16; ++r)
                saB[s][r] = __builtin_amdgcn_exp2f(saB[s][r]);
#pragma unroll
        for (int s = 0; s < 2; ++s) {
            unsigned int wv[8];
#pragma unroll
            for (int g = 0; g < 8; ++g)
                wv[g] = cvtpk(saB[s][g * 2], saB[s][g * 2 + 1]);
            plswap(wv[0], wv[2]); plswap(wv[1], wv[3]);
            plswap(wv[4], wv[6]); plswap(wv[5], wv[7]);
            union { unsigned int u[4]; short8 s8; } f0, f1;
            f0.u[0] = wv[0]; f0.u[1] = wv[1]; f0.u[2] = wv[2]; f0.u[3] = wv[3];
            f1.u[0] = wv[4]; f1.u[1] = wv[5]; f1.u[2] = wv[6]; f1.u[3] = wv[7];
            __builtin_amdgcn_s_setprio(1);
            lacc = __builtin_amdgcn_mfma_f32_32x32x16_bf16(ones, f0.s8, lacc, 0, 0, 0);
            lacc = __builtin_amdgcn_mfma_f32_32x32x16_bf16(ones, f1.s8, lacc, 0, 0, 0);
#pragma unroll
            for (int dt = 0; dt < 2; ++dt) {
                const short8 v0 = *(const short8*)(VbB + (dt * 4 + s * 2 + 0) * 512 + l * 8);
                oacc[dt] = __builtin_amdgcn_mfma_f32_32x32x16_bf16(v0, f0.s8, oacc[dt], 0, 0, 0);
                const short8 v1 = *(const short8*)(VbB + (dt * 4 + s * 2 + 1) * 512 + l * 8);
                oacc[dt] = __builtin_amdgcn_mfma_f32_32x32x16_bf16(v1, f1.s8, oacc[dt], 0, 0, 0);
            }
            __builtin_amdgcn_s_setprio(0);
        }

        // pipeline control (2-deep, stage-at-end)
        if (c < 14) {
            asm volatile("s_waitcnt lgkmcnt(0)" ::: "memory");  // own LDS reads retired
            __builtin_amdgcn_s_barrier();                       // all waves' reads retired
            stage(buf, c + 2);                                  // restage this buffer
            asm volatile("s_waitcnt vmcnt(8)" ::: "memory");    // chunk c+1 landed (counted)
            __builtin_amdgcn_s_barrier();
        } else if (c == 14) {
            asm volatile("s_waitcnt lgkmcnt(0)" ::: "memory");
            __builtin_amdgcn_s_barrier();
            asm volatile("s_waitcnt vmcnt(0)" ::: "memory");    // chunk 15 fully landed
            __builtin_amdgcn_s_barrier();
        }
    }

    // epilogue: O/lr; lane's lr = lacc[0] (all regs equal; lanes l, l+32 same q)
    const float inv = 1.0f / lacc[0];
    char* outp = (char*)aout + ((size_t)(b * 2048 + q0 + l31) * 1024 + h * 64) * 2;
#pragma unroll
    for (int dt = 0; dt < 2; ++dt)
#pragma unroll
        for (int rg = 0; rg < 4; ++rg) {
            u32x2 pkd;
            pkd[0] = cvtpk(oacc[dt][rg * 4 + 0] * inv, oacc[dt][rg * 4 + 1] * inv);
            pkd[1] = cvtpk(oacc[dt][rg * 4 + 2] * inv, oacc[dt][rg * 4 + 3] * inv);
            *(u32x2*)(outp + (size_t)(dt * 32 + rg * 8 + hi * 4) * 2) = pkd;
        }
}

extern "C" void kernel_launch(void* const* d_in, const int* in_sizes, int n_in,
                              void* d_out, int out_size, void* d_ws, size_t ws_size,
                              hipStream_t stream) {
    const float* x      = (const float*)d_in[0];
    const float* ps     = (const float*)d_in[1];
    const float* qkv_w  = (const float*)d_in[2];
    const float* qkv_b  = (const float*)d_in[3];
    const float* proj_w = (const float*)d_in[4];
    const float* proj_b = (const float*)d_in[5];
    const float* pw     = (const float*)d_in[6];
    float* out = (float*)d_out;
    char* ws = (char*)d_ws;

    unsigned short* x_bf    = (unsigned short*)(ws);                   // 8 MB (reused: attn_bf)
    unsigned short* w1_bf   = (unsigned short*)(ws + (8u  << 20));     // 6 MB
    unsigned short* wp_bf   = (unsigned short*)(ws + (14u << 20));     // 2 MB
    unsigned short* qb      = (unsigned short*)(ws + (16u << 20));     // 8 MB
    unsigned short* kfrag   = (unsigned short*)(ws + (24u << 20));     // 8 MB
    unsigned short* vfrag   = (unsigned short*)(ws + (32u << 20));     // 8 MB
    unsigned short* attn_bf = x_bf;                                    // x_bf dead after gemm_qkv

    cvt_all_kernel<<<8192, 256, 0, stream>>>(x, qkv_w, proj_w, x_bf, w1_bf, wp_bf);
    gemm_qkv<<<dim3(16, 16), 768, 0, stream>>>(x_bf, w1_bf, qkv_b, ps, pw, qb, kfrag, vfrag);
    attn_kernel<<<dim3(16, 32), 256, 0, stream>>>(qb, kfrag, vfrag, attn_bf);
    gemm_proj<<<dim3(32, 8), 256, 0, stream>>>(attn_bf, wp_bf, proj_b, out);
}